// Round 1
// baseline (426.901 us; speedup 1.0000x reference)
//
#include <hip/hip_runtime.h>
#include <math.h>

// HairBundle SDE drift+diffusion, fp32 elementwise, B=8,000,000 rows of 5 vars.
// out = drift[B,5] flat ++ diffusion[B,5] flat.
//
// R3 changes vs R2 (theory: kernel is LDS/issue-bound, not HBM-bound):
//  1. Strided per-thread row mapping (i + r*THREADS): lane stride 5 dwords
//     -> 2 lanes/bank (free) instead of 20 dwords -> 8-way bank conflict.
//  2. Async global->LDS staging via __builtin_amdgcn_global_load_lds width=16
//     (no VGPR round-trip, no ds_write_b128, loads stream while we do other work).
//  3. Diffusion stores (independent of x) issued between the async load issue
//     and the first barrier, overlapping the staging latency.

typedef float f4 __attribute__((ext_vector_type(4)));
typedef unsigned int u32;

#define THREADS         128
#define ROWS_PER_BLOCK  512                         // 512 rows * 5 fl = 640 float4
#define F4_PER_BLOCK    (ROWS_PER_BLOCK * 5 / 4)    // 640
#define F4_PER_THREAD   (F4_PER_BLOCK / THREADS)    // 5
#define ROWS_PER_THREAD (ROWS_PER_BLOCK / THREADS)  // 4

__global__ __launch_bounds__(THREADS) void hb_sde_kernel(
    const float* __restrict__ t,
    const float* __restrict__ x,
    float* __restrict__ drift,
    float* __restrict__ diff)
{
    __shared__ float lds[ROWS_PER_BLOCK * 5];       // 10 KB -> 16 blocks/CU (160 KB exact)

    const int i = threadIdx.x;
    const long long f4base = (long long)blockIdx.x * F4_PER_BLOCK;

    const f4* __restrict__ xv = (const f4*)x + f4base;
    f4* lv = (f4*)lds;

    // ---- async global -> LDS staging, 16 B/lane/issue ----
    // Lane l of wave w at iter k writes LDS bytes (64w + 128k)*16 + 16*l:
    // exactly the HW's wave-uniform-base + lane*16 pattern (linear LDS).
#pragma unroll
    for (int k = 0; k < F4_PER_THREAD; ++k) {
        const __attribute__((address_space(1))) u32* gsrc =
            (const __attribute__((address_space(1))) u32*)&xv[i + k * THREADS];
        __attribute__((address_space(3))) u32* ldst =
            (__attribute__((address_space(3))) u32*)&lv[i + k * THREADS];
        __builtin_amdgcn_global_load_lds(gsrc, ldst, 16, 0, 0);
    }

    // wave-uniform sinusoidal drive (VALU work under the in-flight loads)
    const float force = 0.5f * sinf(6.283185307179586f * t[0]);

    // ---- diffusion: constant pattern, independent of x -> overlap with loads ----
    // float4 index g covers floats 4g..4g+3; value at float p is c[p%5],
    // c = {0.05, 0.02, 0, 0, 0}. F4_PER_BLOCK=640 divisible by 5, so
    // g % 5 == (i + k*THREADS) % 5 (block-independent).
    f4* __restrict__ gv = (f4*)diff + f4base;
#pragma unroll
    for (int k = 0; k < F4_PER_THREAD; ++k) {
        const int m = (i + k * THREADS) % 5;
        f4 v;
        v.x = (m == 0) ? 0.05f : ((m == 4) ? 0.02f : 0.0f);
        v.y = (m == 0) ? 0.02f : ((m == 1) ? 0.05f : 0.0f);
        v.z = (m == 1) ? 0.02f : ((m == 2) ? 0.05f : 0.0f);
        v.w = (m == 2) ? 0.02f : ((m == 3) ? 0.05f : 0.0f);
        __builtin_nontemporal_store(v, &gv[i + k * THREADS]);
    }

    __syncthreads();   // emits s_waitcnt vmcnt(0) -> staged LDS data visible

    // ---- compute: strided rows, lane stride = 5 dwords -> conflict-free ----
#pragma unroll
    for (int r = 0; r < ROWS_PER_THREAD; ++r) {
        const int o = (i + r * THREADS) * 5;
        const float x_hb = lds[o + 0];
        const float x_a  = lds[o + 1];
        const float p_m  = lds[o + 2];
        const float p_gs = lds[o + 3];
        const float p_t  = lds[o + 4];

        // p_o = sigmoid((x_hb - x_a)/DELTA), DELTA = 0.25
        const float p_o  = 1.0f / (1.0f + __expf(-4.0f * (x_hb - x_a)));
        // f_gs = K_GS*(x_hb - x_a - D_GATE*p_o)
        const float f_gs = 0.75f * (x_hb - x_a - 0.5f * p_o);

        lds[o + 0] = -f_gs - 0.6f * x_hb + force;
        lds[o + 1] = 0.1f * (f_gs - 0.45f * x_a - 0.35f * (1.0f - 0.9f * p_m));
        lds[o + 2] = 1.2f * p_o * (1.0f - p_m)  - 0.8f * p_m;
        lds[o + 3] = 0.7f * p_o * (1.0f - p_gs) - 0.5f * p_gs;
        lds[o + 4] = 0.3f * p_o * (1.0f - p_t)  - 0.4f * p_t;
    }
    __syncthreads();

    // ---- coalesced LDS -> global drift ----
    f4* __restrict__ dv = (f4*)drift + f4base;
#pragma unroll
    for (int k = 0; k < F4_PER_THREAD; ++k)
        __builtin_nontemporal_store(lv[i + k * THREADS], &dv[i + k * THREADS]);
}

extern "C" void kernel_launch(void* const* d_in, const int* in_sizes, int n_in,
                              void* d_out, int out_size, void* d_ws, size_t ws_size,
                              hipStream_t stream) {
    const float* t = (const float*)d_in[0];
    const float* x = (const float*)d_in[1];
    float* out = (float*)d_out;

    const long long batch = (long long)in_sizes[1] / 5;   // 8,000,000
    float* drift = out;
    float* diff  = out + batch * 5;

    const int nblocks = (int)(batch / ROWS_PER_BLOCK);    // 15625, exact
    hb_sde_kernel<<<nblocks, THREADS, 0, stream>>>(t, x, drift, diff);
}

// Round 2
// 421.415 us; speedup vs baseline: 1.0130x; 1.0130x over previous
//
#include <hip/hip_runtime.h>
#include <math.h>

// HairBundle SDE drift+diffusion, fp32 elementwise, B=8,000,000 rows of 5 vars.
// out = drift[B,5] flat ++ diffusion[B,5] flat.
//
// R4 change vs R3 (A/B on the one untested inherited decision):
//  - Remove ALL __builtin_nontemporal_* hints. The two 6.3-6.4 TB/s
//    references on this chip (harness fill, m13 float4 copy) use plain
//    cached stores; our NT-hinted kernel runs at ~2.5-3 TB/s. Theory:
//    the `nt` flag degrades L2 write-combining on this 3-stream pattern.
//  - Everything else kept from R3: async global_load_lds staging (16B),
//    conflict-free strided row mapping (lane stride 5 dwords),
//    diffusion stores overlapped with in-flight staging loads.

typedef float f4 __attribute__((ext_vector_type(4)));
typedef unsigned int u32;

#define THREADS         128
#define ROWS_PER_BLOCK  512                         // 512 rows * 5 fl = 640 float4
#define F4_PER_BLOCK    (ROWS_PER_BLOCK * 5 / 4)    // 640
#define F4_PER_THREAD   (F4_PER_BLOCK / THREADS)    // 5
#define ROWS_PER_THREAD (ROWS_PER_BLOCK / THREADS)  // 4

__global__ __launch_bounds__(THREADS) void hb_sde_kernel(
    const float* __restrict__ t,
    const float* __restrict__ x,
    float* __restrict__ drift,
    float* __restrict__ diff)
{
    __shared__ float lds[ROWS_PER_BLOCK * 5];       // 10 KB -> 16 blocks/CU (160 KB exact)

    const int i = threadIdx.x;
    const long long f4base = (long long)blockIdx.x * F4_PER_BLOCK;

    const f4* __restrict__ xv = (const f4*)x + f4base;
    f4* lv = (f4*)lds;

    // ---- async global -> LDS staging, 16 B/lane/issue (cached, aux=0) ----
#pragma unroll
    for (int k = 0; k < F4_PER_THREAD; ++k) {
        const __attribute__((address_space(1))) u32* gsrc =
            (const __attribute__((address_space(1))) u32*)&xv[i + k * THREADS];
        __attribute__((address_space(3))) u32* ldst =
            (__attribute__((address_space(3))) u32*)&lv[i + k * THREADS];
        __builtin_amdgcn_global_load_lds(gsrc, ldst, 16, 0, 0);
    }

    // wave-uniform sinusoidal drive (VALU work under the in-flight loads)
    const float force = 0.5f * sinf(6.283185307179586f * t[0]);

    // ---- diffusion: constant pattern, independent of x -> overlap with loads ----
    // float4 index g covers floats 4g..4g+3; value at float p is c[p%5],
    // c = {0.05, 0.02, 0, 0, 0}. F4_PER_BLOCK=640 divisible by 5, so
    // g % 5 == (i + k*THREADS) % 5 (block-independent).
    f4* __restrict__ gv = (f4*)diff + f4base;
#pragma unroll
    for (int k = 0; k < F4_PER_THREAD; ++k) {
        const int m = (i + k * THREADS) % 5;
        f4 v;
        v.x = (m == 0) ? 0.05f : ((m == 4) ? 0.02f : 0.0f);
        v.y = (m == 0) ? 0.02f : ((m == 1) ? 0.05f : 0.0f);
        v.z = (m == 1) ? 0.02f : ((m == 2) ? 0.05f : 0.0f);
        v.w = (m == 2) ? 0.02f : ((m == 3) ? 0.05f : 0.0f);
        gv[i + k * THREADS] = v;                    // plain cached store
    }

    __syncthreads();   // s_waitcnt vmcnt(0) -> staged LDS data visible

    // ---- compute: strided rows, lane stride = 5 dwords -> conflict-free ----
#pragma unroll
    for (int r = 0; r < ROWS_PER_THREAD; ++r) {
        const int o = (i + r * THREADS) * 5;
        const float x_hb = lds[o + 0];
        const float x_a  = lds[o + 1];
        const float p_m  = lds[o + 2];
        const float p_gs = lds[o + 3];
        const float p_t  = lds[o + 4];

        // p_o = sigmoid((x_hb - x_a)/DELTA), DELTA = 0.25
        const float p_o  = 1.0f / (1.0f + __expf(-4.0f * (x_hb - x_a)));
        // f_gs = K_GS*(x_hb - x_a - D_GATE*p_o)
        const float f_gs = 0.75f * (x_hb - x_a - 0.5f * p_o);

        lds[o + 0] = -f_gs - 0.6f * x_hb + force;
        lds[o + 1] = 0.1f * (f_gs - 0.45f * x_a - 0.35f * (1.0f - 0.9f * p_m));
        lds[o + 2] = 1.2f * p_o * (1.0f - p_m)  - 0.8f * p_m;
        lds[o + 3] = 0.7f * p_o * (1.0f - p_gs) - 0.5f * p_gs;
        lds[o + 4] = 0.3f * p_o * (1.0f - p_t)  - 0.4f * p_t;
    }
    __syncthreads();

    // ---- coalesced LDS -> global drift (plain cached stores) ----
    f4* __restrict__ dv = (f4*)drift + f4base;
#pragma unroll
    for (int k = 0; k < F4_PER_THREAD; ++k)
        dv[i + k * THREADS] = lv[i + k * THREADS];
}

extern "C" void kernel_launch(void* const* d_in, const int* in_sizes, int n_in,
                              void* d_out, int out_size, void* d_ws, size_t ws_size,
                              hipStream_t stream) {
    const float* t = (const float*)d_in[0];
    const float* x = (const float*)d_in[1];
    float* out = (float*)d_out;

    const long long batch = (long long)in_sizes[1] / 5;   // 8,000,000
    float* drift = out;
    float* diff  = out + batch * 5;

    const int nblocks = (int)(batch / ROWS_PER_BLOCK);    // 15625, exact
    hb_sde_kernel<<<nblocks, THREADS, 0, stream>>>(t, x, drift, diff);
}